// Round 19
// baseline (142.872 us; speedup 1.0000x reference)
//
#include <hip/hip_runtime.h>
#include <hip/hip_fp16.h>
#include <math.h>

typedef _Float16 f16x8 __attribute__((ext_vector_type(8)));
typedef float f32x4 __attribute__((ext_vector_type(4)));

constexpr int SCAN_TPB = 256;
constexpr int SCAN_EPT = 8;                      // elements per thread
constexpr int SCAN_EPB = SCAN_TPB * SCAN_EPT;    // 2048 per block

// ---------------- init: W2 -> fp16^T, zero deg / scan slots ----------------
__global__ __launch_bounds__(256) void k_init(const float* __restrict__ W2,
                                              __half* __restrict__ w2t,
                                              int* __restrict__ deg,
                                              int* __restrict__ slots, int nb, int n) {
    int idx = blockIdx.x * 256 + threadIdx.x;
    if (idx < 128 * 64) {
        int k = idx >> 6, f = idx & 63;
        w2t[f * 128 + k] = __float2half(W2[idx]);
    }
    if (idx < nb) slots[idx] = 0;                  // lookback slots
    int stride = gridDim.x * 256;
    int n4 = n >> 2;
    int4* d4 = reinterpret_cast<int4*>(deg);
    for (int j = idx; j < n4; j += stride) d4[j] = make_int4(0, 0, 0, 0);
    for (int j = (n4 << 2) + idx; j < n; j += stride) deg[j] = 0;
}

// ---------------- degree (in-degree over dst) ----------------
__global__ void k_deg(const int* __restrict__ dst, int* __restrict__ deg, int E) {
    int i = blockIdx.x * blockDim.x + threadIdx.x;
    if (i < E) atomicAdd(&deg[dst[i]], 1);
}

// ---------------- single-kernel scan (decoupled lookback) + fused dinv/xsc ----------
__global__ __launch_bounds__(SCAN_TPB) void k_scan(const int* __restrict__ deg,
                                                   int* __restrict__ slots, int nb,
                                                   int* __restrict__ row_off,
                                                   int* __restrict__ cursor,
                                                   const float2* __restrict__ x2,
                                                   float* __restrict__ dinv,
                                                   float2* __restrict__ xsc, int n) {
    int t = threadIdx.x, lane = t & 63, wid = t >> 6;
    int bid = blockIdx.x;
    __shared__ int wsum[4], wscan[4];
    __shared__ int s_add, s_agg;

    int idx0 = bid * SCAN_EPB + t * SCAN_EPT;
    int e[SCAN_EPT];
    bool full = (idx0 + SCAN_EPT <= n);
    if (full) {
        const int4* p = reinterpret_cast<const int4*>(deg + idx0);
        int4 a = p[0], b = p[1];
        e[0] = a.x; e[1] = a.y; e[2] = a.z; e[3] = a.w;
        e[4] = b.x; e[5] = b.y; e[6] = b.z; e[7] = b.w;
    } else {
        for (int k = 0; k < SCAN_EPT; ++k) { int i = idx0 + k; e[k] = (i < n) ? deg[i] : 0; }
    }
    // fused dinv + xsc
#pragma unroll
    for (int k = 0; k < SCAN_EPT; ++k) {
        int i = idx0 + k;
        if (i < n) {
            float di = rsqrtf((float)e[k] + 1.0f);  // +1 self loop
            dinv[i] = di;
            float2 xv = x2[i];
            xsc[i] = make_float2(xv.x * di, xv.y * di);
        }
    }
    int tsum = 0;
#pragma unroll
    for (int k = 0; k < SCAN_EPT; ++k) tsum += e[k];
    // block aggregate
    int r = tsum;
#pragma unroll
    for (int off = 32; off; off >>= 1) r += __shfl_xor(r, off);
    if (lane == 0) wsum[wid] = r;
    __syncthreads();
    if (t == 0) {
        int agg = wsum[0] + wsum[1] + wsum[2] + wsum[3];
        s_agg = agg;
        atomicExch(&slots[bid], (agg << 1) | 1);   // publish (value|ready in one word)
    }
    // wave 0: parallel lookback over predecessors
    if (wid == 0) {
        int acc = 0;
        for (int base = 0; base < bid; base += 64) {
            int j = base + lane;
            if (j < bid) {
                int v;
                do { v = atomicAdd(&slots[j], 0); } while (!(v & 1));
                acc += v >> 1;
            }
        }
#pragma unroll
        for (int off = 32; off; off >>= 1) acc += __shfl_xor(acc, off);
        if (lane == 0) s_add = acc;
    }
    __syncthreads();
    if (t == 0 && bid == (int)gridDim.x - 1) row_off[n] = s_add + s_agg;

    // intra-block exclusive scan
    int s = tsum;
#pragma unroll
    for (int off = 1; off < 64; off <<= 1) { int u = __shfl_up(s, off); if (lane >= off) s += u; }
    if (lane == 63) wscan[wid] = s;
    __syncthreads();
    int add = s_add;
    for (int w = 0; w < wid; ++w) add += wscan[w];
    int run = s - tsum + add;
    int o[SCAN_EPT];
#pragma unroll
    for (int k = 0; k < SCAN_EPT; ++k) { o[k] = run; run += e[k]; }
    if (full) {
        int4* ro = reinterpret_cast<int4*>(row_off + idx0);
        int4* cu = reinterpret_cast<int4*>(cursor + idx0);
        ro[0] = make_int4(o[0], o[1], o[2], o[3]);
        ro[1] = make_int4(o[4], o[5], o[6], o[7]);
        cu[0] = make_int4(o[0], o[1], o[2], o[3]);
        cu[1] = make_int4(o[4], o[5], o[6], o[7]);
    } else {
        for (int k = 0; k < SCAN_EPT; ++k) {
            int i = idx0 + k;
            if (i < n) { row_off[i] = o[k]; cursor[i] = o[k]; }
        }
    }
}

// ---------------- CSR fill (counting sort by dst) ----------------
__global__ void k_fill(const int* __restrict__ src, const int* __restrict__ dst,
                       int* __restrict__ cursor, int* __restrict__ csr_src, int E) {
    int e = blockIdx.x * blockDim.x + threadIdx.x;
    if (e < E) {
        int pos = atomicAdd(&cursor[dst[e]], 1);
        csr_src[pos] = src[e];
    }
}

// ---------------- layer-1 fused: agg + MLP on MFMA ----------------
// Round-19: k_agg1 absorbed. Each lane gathers its node's neighbors from
// L2-resident xsc (deg~3, 8B each; kg-duplicate lanes redo it -- trivial L2
// traffic, latency hidden by 8 waves/SIMD). Gather-fusion is safe; round-17's
// failure was SCATTER-fusion.
__global__ __launch_bounds__(256, 2) void k_gemm1m(
    const float2* __restrict__ xsc, const float* __restrict__ dinv,
    const int* __restrict__ row_off, const int* __restrict__ csr_src,
    const float* __restrict__ W1, const float* __restrict__ b1,
    const __half* __restrict__ w2t, __half* __restrict__ m2h, int n) {
    __shared__ __align__(16) float cs[4][16][68];
    int tid = threadIdx.x;
    int w = tid >> 6, lane = tid & 63;
    int col = lane & 15, kg = lane >> 4;
    int base = (blockIdx.x * 4 + w) * 16;          // 16 nodes per wave

    f16x8 bf[4][4];                                // B frags [f-tile][k-step]
#pragma unroll
    for (int ft = 0; ft < 4; ++ft)
#pragma unroll
        for (int t = 0; t < 4; ++t)
            bf[ft][t] = *reinterpret_cast<const f16x8*>(
                w2t + (ft * 16 + col) * 128 + t * 32 + kg * 8);

    int an = base + col; if (an >= n) an = 0;      // A row (clamped; store guarded)
    // inline layer-1 aggregation: xa = dinv*(xsc_self + sum_nbr xsc)
    float2 self = xsc[an];
    float xa0 = self.x, xa1 = self.y;
    {
        int r0 = row_off[an], r1 = row_off[an + 1];
        for (int j = r0; j < r1; ++j) {
            float2 v = xsc[csr_src[j]];            // L2-resident 8B gather
            xa0 += v.x; xa1 += v.y;
        }
    }
    float diA = dinv[an];
    float2 xa = make_float2(xa0 * diA, xa1 * diA);
    f32x4 c0 = {}, c1 = {}, c2 = {}, c3 = {};
#pragma unroll
    for (int t = 0; t < 4; ++t) {
        int k0 = t * 32 + kg * 8;
        float4 wa0 = *reinterpret_cast<const float4*>(&W1[k0]);
        float4 wa1 = *reinterpret_cast<const float4*>(&W1[k0 + 4]);
        float4 wb0 = *reinterpret_cast<const float4*>(&W1[128 + k0]);
        float4 wb1 = *reinterpret_cast<const float4*>(&W1[128 + k0 + 4]);
        float4 bb0 = *reinterpret_cast<const float4*>(&b1[k0]);
        float4 bb1 = *reinterpret_cast<const float4*>(&b1[k0 + 4]);
        f16x8 a;
        a[0] = (_Float16)fmaxf(fmaf(xa.y, wb0.x, fmaf(xa.x, wa0.x, bb0.x)), 0.f);
        a[1] = (_Float16)fmaxf(fmaf(xa.y, wb0.y, fmaf(xa.x, wa0.y, bb0.y)), 0.f);
        a[2] = (_Float16)fmaxf(fmaf(xa.y, wb0.z, fmaf(xa.x, wa0.z, bb0.z)), 0.f);
        a[3] = (_Float16)fmaxf(fmaf(xa.y, wb0.w, fmaf(xa.x, wa0.w, bb0.w)), 0.f);
        a[4] = (_Float16)fmaxf(fmaf(xa.y, wb1.x, fmaf(xa.x, wa1.x, bb1.x)), 0.f);
        a[5] = (_Float16)fmaxf(fmaf(xa.y, wb1.y, fmaf(xa.x, wa1.y, bb1.y)), 0.f);
        a[6] = (_Float16)fmaxf(fmaf(xa.y, wb1.z, fmaf(xa.x, wa1.z, bb1.z)), 0.f);
        a[7] = (_Float16)fmaxf(fmaf(xa.y, wb1.w, fmaf(xa.x, wa1.w, bb1.w)), 0.f);
        c0 = __builtin_amdgcn_mfma_f32_16x16x32_f16(a, bf[0][t], c0, 0, 0, 0);
        c1 = __builtin_amdgcn_mfma_f32_16x16x32_f16(a, bf[1][t], c1, 0, 0, 0);
        c2 = __builtin_amdgcn_mfma_f32_16x16x32_f16(a, bf[2][t], c2, 0, 0, 0);
        c3 = __builtin_amdgcn_mfma_f32_16x16x32_f16(a, bf[3][t], c3, 0, 0, 0);
    }
#pragma unroll
    for (int r = 0; r < 4; ++r) {                  // C row = kg*4+r, col = ft*16+col
        cs[w][kg * 4 + r][0 * 16 + col] = c0[r];
        cs[w][kg * 4 + r][1 * 16 + col] = c1[r];
        cs[w][kg * 4 + r][2 * 16 + col] = c2[r];
        cs[w][kg * 4 + r][3 * 16 + col] = c3[r];
    }
    __syncthreads();
    int nl = tid >> 2, ch = tid & 3;               // node-in-block, 16-feature chunk
    int node = blockIdx.x * 64 + nl;
    if (node < n) {
        float di = dinv[node];
        const float* row = &cs[nl >> 4][nl & 15][ch * 16];
        union { __half2 h2v[8]; int4 q[2]; } u;
#pragma unroll
        for (int j = 0; j < 8; ++j)
            u.h2v[j] = __floats2half2_rn(row[2 * j] * di, row[2 * j + 1] * di);
        int4* dst = reinterpret_cast<int4*>(m2h + (size_t)node * 64 + ch * 16);
        dst[0] = u.q[0]; dst[1] = u.q[1];
    }
}

// ---------------- layer 2 gather + full epilogue ----------------
// 8 nodes/wave, 8-lane group per node; packed fp16 accumulation; 4 predicated
// gathers in flight per batch.
__global__ __launch_bounds__(256) void k_l2out(
    const __half* __restrict__ m2h, const float* __restrict__ dinv,
    const int* __restrict__ row_off, const int* __restrict__ csr_src,
    const float* __restrict__ b2, const float* __restrict__ Wp,
    const float* __restrict__ bp, float* __restrict__ out, int n) {
    int tid = threadIdx.x;
    int wid = tid >> 6, lane = tid & 63;
    int g = lane >> 3;                             // node sub-slot 0..7
    int f8 = lane & 7;                             // feature octet 0..7
    int i = (blockIdx.x * 4 + wid) * 8 + g;
    bool valid = i < n;
    int ic = valid ? i : 0;
    int r0 = row_off[ic];
    int r1 = valid ? row_off[ic + 1] : r0;
    // self row initializes accumulator set A (the +self term, exact)
    int4 sv = *reinterpret_cast<const int4*>(m2h + (size_t)ic * 64 + f8 * 8);
    const __half2* sh = reinterpret_cast<const __half2*>(&sv);
    __half2 a0 = sh[0], a1 = sh[1], a2 = sh[2], a3 = sh[3];
    __half2 z; z.x = __ushort_as_half((unsigned short)0); z.y = z.x;
    __half2 b0 = z, b1 = z, b2v_ = z, b3 = z;
    for (int j = r0; j < r1; j += 4) {             // 4 gathers in flight per batch
        bool d1 = j + 1 < r1, d2 = j + 2 < r1, d3 = j + 3 < r1;
        int s0 = csr_src[j];
        int s1 = d1 ? csr_src[j + 1] : 0;
        int s2 = d2 ? csr_src[j + 2] : 0;
        int s3 = d3 ? csr_src[j + 3] : 0;
        int4 v0, v1, v2, v3;
        v0 = *reinterpret_cast<const int4*>(m2h + (size_t)s0 * 64 + f8 * 8);
        if (d1) v1 = *reinterpret_cast<const int4*>(m2h + (size_t)s1 * 64 + f8 * 8);
        if (d2) v2 = *reinterpret_cast<const int4*>(m2h + (size_t)s2 * 64 + f8 * 8);
        if (d3) v3 = *reinterpret_cast<const int4*>(m2h + (size_t)s3 * 64 + f8 * 8);
        {
            const __half2* h0 = reinterpret_cast<const __half2*>(&v0);
            a0 = __hadd2(a0, h0[0]); a1 = __hadd2(a1, h0[1]);
            a2 = __hadd2(a2, h0[2]); a3 = __hadd2(a3, h0[3]);
        }
        if (d1) {
            const __half2* h1 = reinterpret_cast<const __half2*>(&v1);
            b0 = __hadd2(b0, h1[0]); b1 = __hadd2(b1, h1[1]);
            b2v_ = __hadd2(b2v_, h1[2]); b3 = __hadd2(b3, h1[3]);
        }
        if (d2) {
            const __half2* h2 = reinterpret_cast<const __half2*>(&v2);
            a0 = __hadd2(a0, h2[0]); a1 = __hadd2(a1, h2[1]);
            a2 = __hadd2(a2, h2[2]); a3 = __hadd2(a3, h2[3]);
        }
        if (d3) {
            const __half2* h3 = reinterpret_cast<const __half2*>(&v3);
            b0 = __hadd2(b0, h3[0]); b1 = __hadd2(b1, h3[1]);
            b2v_ = __hadd2(b2v_, h3[2]); b3 = __hadd2(b3, h3[3]);
        }
    }
    a0 = __hadd2(a0, b0); a1 = __hadd2(a1, b1);
    a2 = __hadd2(a2, b2v_); a3 = __hadd2(a3, b3);
    float2 f0 = __half22float2(a0), f1 = __half22float2(a1);
    float2 f2 = __half22float2(a2), f3 = __half22float2(a3);
    float di = dinv[ic];
    float4 b2a = reinterpret_cast<const float4*>(b2)[f8 * 2];
    float4 b2b = reinterpret_cast<const float4*>(b2)[f8 * 2 + 1];
    float4 wpa = reinterpret_cast<const float4*>(Wp)[f8 * 2];
    float4 wpb = reinterpret_cast<const float4*>(Wp)[f8 * 2 + 1];
    float v = fmaxf(fmaf(f0.x, di, b2a.x), 0.f) * wpa.x
            + fmaxf(fmaf(f0.y, di, b2a.y), 0.f) * wpa.y
            + fmaxf(fmaf(f1.x, di, b2a.z), 0.f) * wpa.z
            + fmaxf(fmaf(f1.y, di, b2a.w), 0.f) * wpa.w
            + fmaxf(fmaf(f2.x, di, b2b.x), 0.f) * wpb.x
            + fmaxf(fmaf(f2.y, di, b2b.y), 0.f) * wpb.y
            + fmaxf(fmaf(f3.x, di, b2b.z), 0.f) * wpb.z
            + fmaxf(fmaf(f3.y, di, b2b.w), 0.f) * wpb.w;
    v += __shfl_xor(v, 1);                         // reduce the 8-lane group
    v += __shfl_xor(v, 2);
    v += __shfl_xor(v, 4);
    if (valid && f8 == 0) out[i] = 1.f / (1.f + expf(-(v + bp[0])));
}

extern "C" void kernel_launch(void* const* d_in, const int* in_sizes, int n_in,
                              void* d_out, int out_size, void* d_ws, size_t ws_size,
                              hipStream_t stream) {
    const float* x  = (const float*)d_in[0];
    const int*   ei = (const int*)d_in[1];   // [2, E] int32
    const float* W1 = (const float*)d_in[2];
    const float* b1 = (const float*)d_in[3];
    const float* W2 = (const float*)d_in[4];
    const float* b2 = (const float*)d_in[5];
    const float* Wp = (const float*)d_in[6];
    const float* bp = (const float*)d_in[7];
    float* out = (float*)d_out;

    int n = in_sizes[0] / 2;
    int E = in_sizes[1] / 2;
    const int* src = ei;
    const int* dst = ei + E;

    char* ws = (char*)d_ws;
    size_t off = 0;
    auto alloc = [&](size_t bytes) -> void* {
        void* p = ws + off;
        off += (bytes + 255) & ~(size_t)255;
        return p;
    };
    int nb = (n + SCAN_EPB - 1) / SCAN_EPB;
    int*    deg     = (int*)alloc((size_t)n * 4);
    int*    slots   = (int*)alloc((size_t)nb * 4);
    int*    row_off = (int*)alloc((size_t)(n + 1) * 4);
    int*    cursor  = (int*)alloc((size_t)n * 4);
    float*  dinv    = (float*)alloc((size_t)n * 4);
    float2* xsc     = (float2*)alloc((size_t)n * 8);
    int*    csr_src = (int*)alloc((size_t)E * 4);
    __half* w2t     = (__half*)alloc((size_t)128 * 64 * 2);
    __half* m2h     = (__half*)alloc((size_t)n * 64 * 2);
    (void)ws_size;

    k_init  <<<256, 256, 0, stream>>>(W2, w2t, deg, slots, nb, n);
    k_deg   <<<(E + 255) / 256, 256, 0, stream>>>(dst, deg, E);
    k_scan  <<<nb, SCAN_TPB, 0, stream>>>(deg, slots, nb, row_off, cursor,
                                          (const float2*)x, dinv, xsc, n);
    k_fill  <<<(E + 255) / 256, 256, 0, stream>>>(src, dst, cursor, csr_src, E);
    k_gemm1m<<<(n + 63) / 64, 256, 0, stream>>>(xsc, dinv, row_off, csr_src,
                                                W1, b1, w2t, m2h, n);
    k_l2out <<<(n + 31) / 32, 256, 0, stream>>>(m2h, dinv, row_off, csr_src,
                                                b2, Wp, bp, out, n);
}

// Round 20
// 120.833 us; speedup vs baseline: 1.1824x; 1.1824x over previous
//
#include <hip/hip_runtime.h>
#include <hip/hip_fp16.h>
#include <math.h>

typedef _Float16 f16x8 __attribute__((ext_vector_type(8)));
typedef float f32x4 __attribute__((ext_vector_type(4)));

constexpr int SCAN_TPB = 256;
constexpr int SCAN_EPT = 8;                      // elements per thread
constexpr int SCAN_EPB = SCAN_TPB * SCAN_EPT;    // 2048 per block

// ---------------- init: W2 -> fp16^T, zero deg / scan slots ----------------
__global__ __launch_bounds__(256) void k_init(const float* __restrict__ W2,
                                              __half* __restrict__ w2t,
                                              int* __restrict__ deg,
                                              int* __restrict__ slots, int nb, int n) {
    int idx = blockIdx.x * 256 + threadIdx.x;
    if (idx < 128 * 64) {
        int k = idx >> 6, f = idx & 63;
        w2t[f * 128 + k] = __float2half(W2[idx]);
    }
    if (idx < nb) slots[idx] = 0;                  // lookback slots
    int stride = gridDim.x * 256;
    int n4 = n >> 2;
    int4* d4 = reinterpret_cast<int4*>(deg);
    for (int j = idx; j < n4; j += stride) d4[j] = make_int4(0, 0, 0, 0);
    for (int j = (n4 << 2) + idx; j < n; j += stride) deg[j] = 0;
}

// ---------------- degree + per-edge rank (atomic return value) ----------------
// rank[e] = this edge's position within its dst's CSR segment -> k_fill needs
// no atomics at all.
__global__ void k_deg(const int* __restrict__ dst, int* __restrict__ deg,
                      int* __restrict__ rank, int E) {
    int i = blockIdx.x * blockDim.x + threadIdx.x;
    if (i < E) rank[i] = atomicAdd(&deg[dst[i]], 1);
}

// ---------------- single-kernel scan (decoupled lookback) + fused dinv/xsc ----------
__global__ __launch_bounds__(SCAN_TPB) void k_scan(const int* __restrict__ deg,
                                                   int* __restrict__ slots, int nb,
                                                   int* __restrict__ row_off,
                                                   const float2* __restrict__ x2,
                                                   float* __restrict__ dinv,
                                                   float2* __restrict__ xsc, int n) {
    int t = threadIdx.x, lane = t & 63, wid = t >> 6;
    int bid = blockIdx.x;
    __shared__ int wsum[4], wscan[4];
    __shared__ int s_add, s_agg;

    int idx0 = bid * SCAN_EPB + t * SCAN_EPT;
    int e[SCAN_EPT];
    bool full = (idx0 + SCAN_EPT <= n);
    if (full) {
        const int4* p = reinterpret_cast<const int4*>(deg + idx0);
        int4 a = p[0], b = p[1];
        e[0] = a.x; e[1] = a.y; e[2] = a.z; e[3] = a.w;
        e[4] = b.x; e[5] = b.y; e[6] = b.z; e[7] = b.w;
    } else {
        for (int k = 0; k < SCAN_EPT; ++k) { int i = idx0 + k; e[k] = (i < n) ? deg[i] : 0; }
    }
    // fused dinv + xsc
#pragma unroll
    for (int k = 0; k < SCAN_EPT; ++k) {
        int i = idx0 + k;
        if (i < n) {
            float di = rsqrtf((float)e[k] + 1.0f);  // +1 self loop
            dinv[i] = di;
            float2 xv = x2[i];
            xsc[i] = make_float2(xv.x * di, xv.y * di);
        }
    }
    int tsum = 0;
#pragma unroll
    for (int k = 0; k < SCAN_EPT; ++k) tsum += e[k];
    // block aggregate
    int r = tsum;
#pragma unroll
    for (int off = 32; off; off >>= 1) r += __shfl_xor(r, off);
    if (lane == 0) wsum[wid] = r;
    __syncthreads();
    if (t == 0) {
        int agg = wsum[0] + wsum[1] + wsum[2] + wsum[3];
        s_agg = agg;
        atomicExch(&slots[bid], (agg << 1) | 1);   // publish (value|ready in one word)
    }
    // wave 0: parallel lookback over predecessors
    if (wid == 0) {
        int acc = 0;
        for (int base = 0; base < bid; base += 64) {
            int j = base + lane;
            if (j < bid) {
                int v;
                do { v = atomicAdd(&slots[j], 0); } while (!(v & 1));
                acc += v >> 1;
            }
        }
#pragma unroll
        for (int off = 32; off; off >>= 1) acc += __shfl_xor(acc, off);
        if (lane == 0) s_add = acc;
    }
    __syncthreads();
    if (t == 0 && bid == (int)gridDim.x - 1) row_off[n] = s_add + s_agg;

    // intra-block exclusive scan
    int s = tsum;
#pragma unroll
    for (int off = 1; off < 64; off <<= 1) { int u = __shfl_up(s, off); if (lane >= off) s += u; }
    if (lane == 63) wscan[wid] = s;
    __syncthreads();
    int add = s_add;
    for (int w = 0; w < wid; ++w) add += wscan[w];
    int run = s - tsum + add;
    int o[SCAN_EPT];
#pragma unroll
    for (int k = 0; k < SCAN_EPT; ++k) { o[k] = run; run += e[k]; }
    if (full) {
        int4* ro = reinterpret_cast<int4*>(row_off + idx0);
        ro[0] = make_int4(o[0], o[1], o[2], o[3]);
        ro[1] = make_int4(o[4], o[5], o[6], o[7]);
    } else {
        for (int k = 0; k < SCAN_EPT; ++k) {
            int i = idx0 + k;
            if (i < n) row_off[i] = o[k];
        }
    }
}

// ---------------- CSR fill: atomic-free (rank precomputed in k_deg) ----------------
__global__ void k_fill(const int* __restrict__ src, const int* __restrict__ dst,
                       const int* __restrict__ rank, const int* __restrict__ row_off,
                       int* __restrict__ csr_src, int E) {
    int e = blockIdx.x * blockDim.x + threadIdx.x;
    if (e < E) csr_src[row_off[dst[e]] + rank[e]] = src[e];
}

// ---------------- layer-1 sparse aggregation: xam[i] = dinv[i]*(xsc[i] + sum_nbr xsc[s])
// Round-19 lesson: fusing this gather into gemm1m stalls the MFMA kernel
// (occupancy-capped, dependent-chain head). Standalone at full occupancy = 6 µs.
__global__ __launch_bounds__(256) void k_agg1(
    const float2* __restrict__ xsc, const float* __restrict__ dinv,
    const int* __restrict__ row_off, const int* __restrict__ csr_src,
    float2* __restrict__ xam, int n) {
    int i = blockIdx.x * blockDim.x + threadIdx.x;
    if (i >= n) return;
    int r0 = row_off[i], r1 = row_off[i + 1];
    float2 self = xsc[i];
    float xa0 = self.x, xa1 = self.y;
    for (int j = r0; j < r1; ++j) {
        float2 v = xsc[csr_src[j]];               // 8B gather, xsc=1.6MB L2-resident
        xa0 += v.x; xa1 += v.y;
    }
    float di = dinv[i];
    xam[i] = make_float2(xa0 * di, xa1 * di);
}

// ---------------- layer-1 fused MLP on MFMA: m2 = (relu(xam@W1+b1) @ W2) * dinv -----
__global__ __launch_bounds__(256, 2) void k_gemm1m(
    const float2* __restrict__ xam, const float* __restrict__ W1,
    const float* __restrict__ b1, const __half* __restrict__ w2t,
    const float* __restrict__ dinv, __half* __restrict__ m2h, int n) {
    __shared__ __align__(16) float cs[4][16][68];
    int tid = threadIdx.x;
    int w = tid >> 6, lane = tid & 63;
    int col = lane & 15, kg = lane >> 4;
    int base = (blockIdx.x * 4 + w) * 16;          // 16 nodes per wave

    f16x8 bf[4][4];                                // B frags [f-tile][k-step]
#pragma unroll
    for (int ft = 0; ft < 4; ++ft)
#pragma unroll
        for (int t = 0; t < 4; ++t)
            bf[ft][t] = *reinterpret_cast<const f16x8*>(
                w2t + (ft * 16 + col) * 128 + t * 32 + kg * 8);

    int an = base + col; if (an >= n) an = 0;      // A row (clamped; store guarded)
    float2 xa = xam[an];
    f32x4 c0 = {}, c1 = {}, c2 = {}, c3 = {};
#pragma unroll
    for (int t = 0; t < 4; ++t) {
        int k0 = t * 32 + kg * 8;
        float4 wa0 = *reinterpret_cast<const float4*>(&W1[k0]);
        float4 wa1 = *reinterpret_cast<const float4*>(&W1[k0 + 4]);
        float4 wb0 = *reinterpret_cast<const float4*>(&W1[128 + k0]);
        float4 wb1 = *reinterpret_cast<const float4*>(&W1[128 + k0 + 4]);
        float4 bb0 = *reinterpret_cast<const float4*>(&b1[k0]);
        float4 bb1 = *reinterpret_cast<const float4*>(&b1[k0 + 4]);
        f16x8 a;
        a[0] = (_Float16)fmaxf(fmaf(xa.y, wb0.x, fmaf(xa.x, wa0.x, bb0.x)), 0.f);
        a[1] = (_Float16)fmaxf(fmaf(xa.y, wb0.y, fmaf(xa.x, wa0.y, bb0.y)), 0.f);
        a[2] = (_Float16)fmaxf(fmaf(xa.y, wb0.z, fmaf(xa.x, wa0.z, bb0.z)), 0.f);
        a[3] = (_Float16)fmaxf(fmaf(xa.y, wb0.w, fmaf(xa.x, wa0.w, bb0.w)), 0.f);
        a[4] = (_Float16)fmaxf(fmaf(xa.y, wb1.x, fmaf(xa.x, wa1.x, bb1.x)), 0.f);
        a[5] = (_Float16)fmaxf(fmaf(xa.y, wb1.y, fmaf(xa.x, wa1.y, bb1.y)), 0.f);
        a[6] = (_Float16)fmaxf(fmaf(xa.y, wb1.z, fmaf(xa.x, wa1.z, bb1.z)), 0.f);
        a[7] = (_Float16)fmaxf(fmaf(xa.y, wb1.w, fmaf(xa.x, wa1.w, bb1.w)), 0.f);
        c0 = __builtin_amdgcn_mfma_f32_16x16x32_f16(a, bf[0][t], c0, 0, 0, 0);
        c1 = __builtin_amdgcn_mfma_f32_16x16x32_f16(a, bf[1][t], c1, 0, 0, 0);
        c2 = __builtin_amdgcn_mfma_f32_16x16x32_f16(a, bf[2][t], c2, 0, 0, 0);
        c3 = __builtin_amdgcn_mfma_f32_16x16x32_f16(a, bf[3][t], c3, 0, 0, 0);
    }
#pragma unroll
    for (int r = 0; r < 4; ++r) {                  // C row = kg*4+r, col = ft*16+col
        cs[w][kg * 4 + r][0 * 16 + col] = c0[r];
        cs[w][kg * 4 + r][1 * 16 + col] = c1[r];
        cs[w][kg * 4 + r][2 * 16 + col] = c2[r];
        cs[w][kg * 4 + r][3 * 16 + col] = c3[r];
    }
    __syncthreads();
    int nl = tid >> 2, ch = tid & 3;               // node-in-block, 16-feature chunk
    int node = blockIdx.x * 64 + nl;
    if (node < n) {
        float di = dinv[node];
        const float* row = &cs[nl >> 4][nl & 15][ch * 16];
        union { __half2 h2v[8]; int4 q[2]; } u;
#pragma unroll
        for (int j = 0; j < 8; ++j)
            u.h2v[j] = __floats2half2_rn(row[2 * j] * di, row[2 * j + 1] * di);
        int4* dst = reinterpret_cast<int4*>(m2h + (size_t)node * 64 + ch * 16);
        dst[0] = u.q[0]; dst[1] = u.q[1];
    }
}

// ---------------- layer 2 gather + full epilogue ----------------
// 8 nodes/wave, 8-lane group per node; packed fp16 accumulation; 4 predicated
// gathers in flight per batch.
__global__ __launch_bounds__(256) void k_l2out(
    const __half* __restrict__ m2h, const float* __restrict__ dinv,
    const int* __restrict__ row_off, const int* __restrict__ csr_src,
    const float* __restrict__ b2, const float* __restrict__ Wp,
    const float* __restrict__ bp, float* __restrict__ out, int n) {
    int tid = threadIdx.x;
    int wid = tid >> 6, lane = tid & 63;
    int g = lane >> 3;                             // node sub-slot 0..7
    int f8 = lane & 7;                             // feature octet 0..7
    int i = (blockIdx.x * 4 + wid) * 8 + g;
    bool valid = i < n;
    int ic = valid ? i : 0;
    int r0 = row_off[ic];
    int r1 = valid ? row_off[ic + 1] : r0;
    // self row initializes accumulator set A (the +self term, exact)
    int4 sv = *reinterpret_cast<const int4*>(m2h + (size_t)ic * 64 + f8 * 8);
    const __half2* sh = reinterpret_cast<const __half2*>(&sv);
    __half2 a0 = sh[0], a1 = sh[1], a2 = sh[2], a3 = sh[3];
    __half2 z; z.x = __ushort_as_half((unsigned short)0); z.y = z.x;
    __half2 b0 = z, b1 = z, b2v_ = z, b3 = z;
    for (int j = r0; j < r1; j += 4) {             // 4 gathers in flight per batch
        bool d1 = j + 1 < r1, d2 = j + 2 < r1, d3 = j + 3 < r1;
        int s0 = csr_src[j];
        int s1 = d1 ? csr_src[j + 1] : 0;
        int s2 = d2 ? csr_src[j + 2] : 0;
        int s3 = d3 ? csr_src[j + 3] : 0;
        int4 v0, v1, v2, v3;
        v0 = *reinterpret_cast<const int4*>(m2h + (size_t)s0 * 64 + f8 * 8);
        if (d1) v1 = *reinterpret_cast<const int4*>(m2h + (size_t)s1 * 64 + f8 * 8);
        if (d2) v2 = *reinterpret_cast<const int4*>(m2h + (size_t)s2 * 64 + f8 * 8);
        if (d3) v3 = *reinterpret_cast<const int4*>(m2h + (size_t)s3 * 64 + f8 * 8);
        {
            const __half2* h0 = reinterpret_cast<const __half2*>(&v0);
            a0 = __hadd2(a0, h0[0]); a1 = __hadd2(a1, h0[1]);
            a2 = __hadd2(a2, h0[2]); a3 = __hadd2(a3, h0[3]);
        }
        if (d1) {
            const __half2* h1 = reinterpret_cast<const __half2*>(&v1);
            b0 = __hadd2(b0, h1[0]); b1 = __hadd2(b1, h1[1]);
            b2v_ = __hadd2(b2v_, h1[2]); b3 = __hadd2(b3, h1[3]);
        }
        if (d2) {
            const __half2* h2 = reinterpret_cast<const __half2*>(&v2);
            a0 = __hadd2(a0, h2[0]); a1 = __hadd2(a1, h2[1]);
            a2 = __hadd2(a2, h2[2]); a3 = __hadd2(a3, h2[3]);
        }
        if (d3) {
            const __half2* h3 = reinterpret_cast<const __half2*>(&v3);
            b0 = __hadd2(b0, h3[0]); b1 = __hadd2(b1, h3[1]);
            b2v_ = __hadd2(b2v_, h3[2]); b3 = __hadd2(b3, h3[3]);
        }
    }
    a0 = __hadd2(a0, b0); a1 = __hadd2(a1, b1);
    a2 = __hadd2(a2, b2v_); a3 = __hadd2(a3, b3);
    float2 f0 = __half22float2(a0), f1 = __half22float2(a1);
    float2 f2 = __half22float2(a2), f3 = __half22float2(a3);
    float di = dinv[ic];
    float4 b2a = reinterpret_cast<const float4*>(b2)[f8 * 2];
    float4 b2b = reinterpret_cast<const float4*>(b2)[f8 * 2 + 1];
    float4 wpa = reinterpret_cast<const float4*>(Wp)[f8 * 2];
    float4 wpb = reinterpret_cast<const float4*>(Wp)[f8 * 2 + 1];
    float v = fmaxf(fmaf(f0.x, di, b2a.x), 0.f) * wpa.x
            + fmaxf(fmaf(f0.y, di, b2a.y), 0.f) * wpa.y
            + fmaxf(fmaf(f1.x, di, b2a.z), 0.f) * wpa.z
            + fmaxf(fmaf(f1.y, di, b2a.w), 0.f) * wpa.w
            + fmaxf(fmaf(f2.x, di, b2b.x), 0.f) * wpb.x
            + fmaxf(fmaf(f2.y, di, b2b.y), 0.f) * wpb.y
            + fmaxf(fmaf(f3.x, di, b2b.z), 0.f) * wpb.z
            + fmaxf(fmaf(f3.y, di, b2b.w), 0.f) * wpb.w;
    v += __shfl_xor(v, 1);                         // reduce the 8-lane group
    v += __shfl_xor(v, 2);
    v += __shfl_xor(v, 4);
    if (valid && f8 == 0) out[i] = 1.f / (1.f + expf(-(v + bp[0])));
}

extern "C" void kernel_launch(void* const* d_in, const int* in_sizes, int n_in,
                              void* d_out, int out_size, void* d_ws, size_t ws_size,
                              hipStream_t stream) {
    const float* x  = (const float*)d_in[0];
    const int*   ei = (const int*)d_in[1];   // [2, E] int32
    const float* W1 = (const float*)d_in[2];
    const float* b1 = (const float*)d_in[3];
    const float* W2 = (const float*)d_in[4];
    const float* b2 = (const float*)d_in[5];
    const float* Wp = (const float*)d_in[6];
    const float* bp = (const float*)d_in[7];
    float* out = (float*)d_out;

    int n = in_sizes[0] / 2;
    int E = in_sizes[1] / 2;
    const int* src = ei;
    const int* dst = ei + E;

    char* ws = (char*)d_ws;
    size_t off = 0;
    auto alloc = [&](size_t bytes) -> void* {
        void* p = ws + off;
        off += (bytes + 255) & ~(size_t)255;
        return p;
    };
    int nb = (n + SCAN_EPB - 1) / SCAN_EPB;
    int*    deg     = (int*)alloc((size_t)n * 4);
    int*    slots   = (int*)alloc((size_t)nb * 4);
    int*    row_off = (int*)alloc((size_t)(n + 1) * 4);
    int*    rank    = (int*)alloc((size_t)E * 4);
    float*  dinv    = (float*)alloc((size_t)n * 4);
    float2* xsc     = (float2*)alloc((size_t)n * 8);
    float2* xam     = (float2*)alloc((size_t)n * 8);
    int*    csr_src = (int*)alloc((size_t)E * 4);
    __half* w2t     = (__half*)alloc((size_t)128 * 64 * 2);
    __half* m2h     = (__half*)alloc((size_t)n * 64 * 2);
    (void)ws_size;

    k_init  <<<256, 256, 0, stream>>>(W2, w2t, deg, slots, nb, n);
    k_deg   <<<(E + 255) / 256, 256, 0, stream>>>(dst, deg, rank, E);
    k_scan  <<<nb, SCAN_TPB, 0, stream>>>(deg, slots, nb, row_off,
                                          (const float2*)x, dinv, xsc, n);
    k_fill  <<<(E + 255) / 256, 256, 0, stream>>>(src, dst, rank, row_off, csr_src, E);
    k_agg1  <<<(n + 255) / 256, 256, 0, stream>>>(xsc, dinv, row_off, csr_src, xam, n);
    k_gemm1m<<<(n + 63) / 64, 256, 0, stream>>>(xam, W1, b1, w2t, dinv, m2h, n);
    k_l2out <<<(n + 31) / 32, 256, 0, stream>>>(m2h, dinv, row_off, csr_src,
                                                b2, Wp, bp, out, n);
}